// Round 3
// baseline (2122.257 us; speedup 1.0000x reference)
//
#include <hip/hip_runtime.h>

typedef unsigned short u16;
typedef __attribute__((ext_vector_type(8))) short s16x8;
typedef __attribute__((ext_vector_type(4))) float f32x4;

__device__ __forceinline__ float bf2f(u16 u) {
    union { unsigned i; float f; } v; v.i = (unsigned)u << 16; return v.f;
}
__device__ __forceinline__ u16 f2bf(float f) {
    union { float f; unsigned i; } v; v.f = f;
    unsigned r = v.i + 0x7fffu + ((v.i >> 16) & 1u);
    return (u16)(r >> 16);
}
__device__ __forceinline__ f32x4 mfma16(s16x8 a, s16x8 b, f32x4 c) {
    return __builtin_amdgcn_mfma_f32_16x16x32_bf16(a, b, c, 0, 0, 0);
}

// ---------------------------------------------------------------------------
// fp32 -> bf16 conversion
// ---------------------------------------------------------------------------
__global__ __launch_bounds__(256)
void cvt_kernel(const float* __restrict__ src, u16* __restrict__ dst, int n)
{
    for (int i = blockIdx.x * 256 + threadIdx.x; i < n; i += gridDim.x * 256)
        dst[i] = f2bf(src[i]);
}

// ---------------------------------------------------------------------------
// cls rows: h[b, s<12, :] = cls[s] + pos[s]
// ---------------------------------------------------------------------------
__global__ __launch_bounds__(256)
void embed_cls_kernel(const float* __restrict__ cls, const float* __restrict__ pos,
                      float* __restrict__ h32, u16* __restrict__ h16)
{
    int i = blockIdx.x * 256 + threadIdx.x;           // < 128*12*128
    int e = i & 127, s = (i >> 7) % 12, b = i / (12 * 128);
    float v = cls[s * 128 + e] + pos[s * 128 + e];
    size_t o = ((size_t)b * 264 + s) * 128 + e;
    h32[o] = v; h16[o] = f2bf(v);
}

// ---------------------------------------------------------------------------
// Conv-embed via MFMA: rows = (b,l) flat [32256], K=96, N=128.
// Wave owns 32 cols (W in regs); block = 4 waves = 128 cols; loops 4 m-tiles.
// Epilogue fuses conv_b + pos + time_tab/spat_tab gathers.
// ---------------------------------------------------------------------------
__global__ __launch_bounds__(256)
void embed_mfma(const u16* __restrict__ x16, const u16* __restrict__ cw16,
                const float* __restrict__ cb, const float* __restrict__ pos,
                const float* __restrict__ ttab, const float* __restrict__ stab,
                const int* __restrict__ tidx, const int* __restrict__ sidx,
                float* __restrict__ h32, u16* __restrict__ h16)
{
    const int t = threadIdx.x;
    const int wave = t >> 6, lane = t & 63;
    const int quad = lane >> 4, l16 = lane & 15;
    const int n0 = wave * 32;

    s16x8 wf[2][3];
    float bv[2];
    #pragma unroll
    for (int nt = 0; nt < 2; ++nt) {
        bv[nt] = cb[n0 + nt * 16 + l16];
        #pragma unroll
        for (int ks = 0; ks < 3; ++ks)
            wf[nt][ks] = *(const s16x8*)&cw16[(n0 + nt * 16 + l16) * 96 + ks * 32 + quad * 8];
    }
    #pragma unroll
    for (int tt = 0; tt < 4; ++tt) {
        const int m0 = (blockIdx.x * 4 + tt) * 16;
        s16x8 af[3];
        #pragma unroll
        for (int ks = 0; ks < 3; ++ks)
            af[ks] = *(const s16x8*)&x16[(size_t)(m0 + l16) * 96 + ks * 32 + quad * 8];
        f32x4 a0 = (f32x4){0.f,0.f,0.f,0.f}, a1 = (f32x4){0.f,0.f,0.f,0.f};
        #pragma unroll
        for (int ks = 0; ks < 3; ++ks) {
            a0 = mfma16(af[ks], wf[0][ks], a0);
            a1 = mfma16(af[ks], wf[1][ks], a1);
        }
        #pragma unroll
        for (int r = 0; r < 4; ++r) {
            int row = m0 + quad * 4 + r;
            int b = row / 252, l = row - b * 252;
            int ti = tidx[row], si = sidx[row];
            size_t tok = (size_t)b * 264 + 12 + l;
            #pragma unroll
            for (int nt = 0; nt < 2; ++nt) {
                int col = n0 + nt * 16 + l16;
                float v = (nt ? a1[r] : a0[r]) + bv[nt]
                        + pos[(12 + l) * 128 + col]
                        + ttab[ti * 128 + col] + stab[si * 128 + col];
                h32[tok * 128 + col] = v;
                h16[tok * 128 + col] = f2bf(v);
            }
        }
    }
}

// ---------------------------------------------------------------------------
// LDS-free GEMM: C[M,N] = act(A[M,128] @ W[N,128]^T + bias).
// Wave owns 32 cols; W frags register-stationary; loops Tm m-tiles of 16 rows.
// grid = (M/16/Tm, N/128)
// ---------------------------------------------------------------------------
template<bool RELU, int TM>
__global__ __launch_bounds__(256)
void gemm_direct(const u16* __restrict__ A, const u16* __restrict__ W,
                 const float* __restrict__ bias, u16* __restrict__ C, int N)
{
    const int K = 128;
    const int t = threadIdx.x;
    const int wave = t >> 6, lane = t & 63;
    const int quad = lane >> 4, l16 = lane & 15;
    const int n0 = blockIdx.y * 128 + wave * 32;

    s16x8 wf[2][4];
    float bv[2];
    #pragma unroll
    for (int nt = 0; nt < 2; ++nt) {
        bv[nt] = bias[n0 + nt * 16 + l16];
        #pragma unroll
        for (int ks = 0; ks < 4; ++ks)
            wf[nt][ks] = *(const s16x8*)&W[(size_t)(n0 + nt * 16 + l16) * K + ks * 32 + quad * 8];
    }
    #pragma unroll
    for (int tt = 0; tt < TM; ++tt) {
        const int m0 = (blockIdx.x * TM + tt) * 16;
        s16x8 af[4];
        #pragma unroll
        for (int ks = 0; ks < 4; ++ks)
            af[ks] = *(const s16x8*)&A[(size_t)(m0 + l16) * K + ks * 32 + quad * 8];
        f32x4 a0 = (f32x4){0.f,0.f,0.f,0.f}, a1 = (f32x4){0.f,0.f,0.f,0.f};
        #pragma unroll
        for (int ks = 0; ks < 4; ++ks) {
            a0 = mfma16(af[ks], wf[0][ks], a0);
            a1 = mfma16(af[ks], wf[1][ks], a1);
        }
        #pragma unroll
        for (int r = 0; r < 4; ++r) {
            int row = m0 + quad * 4 + r;
            float v0 = a0[r] + bv[0];
            float v1 = a1[r] + bv[1];
            if (RELU) { v0 = fmaxf(v0, 0.f); v1 = fmaxf(v1, 0.f); }
            C[(size_t)row * N + n0 + l16] = f2bf(v0);
            C[(size_t)row * N + n0 + 16 + l16] = f2bf(v1);
        }
    }
}

// ---------------------------------------------------------------------------
// Fused: y = LN(A[M,K] @ W[128,K]^T + bias + resid), write fp32 + bf16.
// bf16 A/W; fp32 bias/resid/g/be. 64-row block, 4 waves; wave owns 16 rows.
// ---------------------------------------------------------------------------
template<int K>
__global__ __launch_bounds__(256)
void gemm_ln(const u16* __restrict__ A, const u16* __restrict__ W,
             const float* __restrict__ bias, const float* resid,
             const float* __restrict__ g, const float* __restrict__ be,
             float* o32, u16* o16)
{
    const int LDK = 136;
    __shared__ alignas(16) u16 As[64 * 136];
    __shared__ alignas(16) u16 Ws[128 * 136];
    const int m0 = blockIdx.x * 64;
    const int t = threadIdx.x;
    const int wave = t >> 6, lane = t & 63;
    const int quad = lane >> 4, l16 = lane & 15;
    const int wr = wave * 16;

    f32x4 acc[8];
    #pragma unroll
    for (int i = 0; i < 8; ++i) acc[i] = (f32x4){0.f, 0.f, 0.f, 0.f};

    for (int kc = 0; kc < K; kc += 128) {
        __syncthreads();
        #pragma unroll
        for (int i = 0; i < 4; ++i) {
            int id = i * 256 + t;
            int row = id >> 4, c8 = (id & 15) << 3;
            *(uint4*)&As[row * LDK + c8] = *(const uint4*)&A[(size_t)(m0 + row) * K + kc + c8];
        }
        #pragma unroll
        for (int i = 0; i < 8; ++i) {
            int id = i * 256 + t;
            int row = id >> 4, c8 = (id & 15) << 3;
            *(uint4*)&Ws[row * LDK + c8] = *(const uint4*)&W[(size_t)row * K + kc + c8];
        }
        __syncthreads();
        #pragma unroll
        for (int ks = 0; ks < 4; ++ks) {
            s16x8 a = *(const s16x8*)&As[(wr + l16) * LDK + ks * 32 + quad * 8];
            #pragma unroll
            for (int nt = 0; nt < 8; ++nt) {
                s16x8 b = *(const s16x8*)&Ws[(nt * 16 + l16) * LDK + ks * 32 + quad * 8];
                acc[nt] = mfma16(a, b, acc[nt]);
            }
        }
    }
    #pragma unroll
    for (int nt = 0; nt < 8; ++nt) {
        int col = nt * 16 + l16;
        float bv = bias[col];
        #pragma unroll
        for (int r = 0; r < 4; ++r) {
            int row = m0 + wr + quad * 4 + r;
            acc[nt][r] += bv + resid[(size_t)row * 128 + col];
        }
    }
    float sm[4], sq[4];
    #pragma unroll
    for (int r = 0; r < 4; ++r) {
        float s = 0.f, q = 0.f;
        #pragma unroll
        for (int nt = 0; nt < 8; ++nt) { float v = acc[nt][r]; s += v; q += v * v; }
        sm[r] = s; sq[r] = q;
    }
    #pragma unroll
    for (int mk = 1; mk < 16; mk <<= 1) {
        #pragma unroll
        for (int r = 0; r < 4; ++r) {
            sm[r] += __shfl_xor(sm[r], mk, 64);
            sq[r] += __shfl_xor(sq[r], mk, 64);
        }
    }
    #pragma unroll
    for (int r = 0; r < 4; ++r) {
        float mean = sm[r] * (1.f / 128.f);
        float var = sq[r] * (1.f / 128.f) - mean * mean;
        float rstd = rsqrtf(var + 1e-5f);
        int row = m0 + wr + quad * 4 + r;
        #pragma unroll
        for (int nt = 0; nt < 8; ++nt) {
            int col = nt * 16 + l16;
            float y = (acc[nt][r] - mean) * rstd * g[col] + be[col];
            o32[(size_t)row * 128 + col] = y;
            o16[(size_t)row * 128 + col] = f2bf(y);
        }
    }
}

// ---------------------------------------------------------------------------
// Attention: one block per (b, head). qkv: [b][s][q0|k128|v256] bf16, head dim 16.
// ---------------------------------------------------------------------------
__global__ __launch_bounds__(256)
void attn_kernel(const u16* __restrict__ qkv, u16* __restrict__ ctx)
{
    const int STR = 296;
    __shared__ alignas(16) u16 VT[16 * 296];   // V transposed [d][key]
    __shared__ alignas(16) u16 Pb[64 * 296];   // per-wave P tiles [16 rows][keys]
    const int b = blockIdx.x >> 3, h = blockIdx.x & 7;
    const size_t base = (size_t)b * 264 * 384;
    const int t = threadIdx.x;
    const int wave = t >> 6, lane = t & 63;
    const int quad = lane >> 4, l16 = lane & 15;
    const int hq = h * 16;

    for (int i = t; i < 264 * 16; i += 256) {
        int s = i >> 4, d = i & 15;
        VT[d * STR + s] = qkv[base + (size_t)s * 384 + 256 + hq + d];
    }
    for (int i = t; i < 16 * 32; i += 256) {
        int d = i >> 5, c = 264 + (i & 31);
        VT[d * STR + c] = 0;
    }
    for (int c = 272 + l16; c < 296; c += 16)
        #pragma unroll
        for (int r = 0; r < 4; ++r)
            Pb[(wave * 16 + quad * 4 + r) * STR + c] = 0;
    __syncthreads();

    for (int qt = wave; qt < 17; qt += 4) {
        const int q0 = qt * 16;
        s16x8 qf = (s16x8){0, 0, 0, 0, 0, 0, 0, 0};
        {
            int srow = q0 + l16;
            if (quad < 2 && srow < 264)
                qf = *(const s16x8*)&qkv[base + (size_t)srow * 384 + hq + quad * 8];
        }
        f32x4 sc[17];
        #pragma unroll
        for (int kt = 0; kt < 17; ++kt) {
            s16x8 kf = (s16x8){0, 0, 0, 0, 0, 0, 0, 0};
            int krow = kt * 16 + l16;
            if (quad < 2 && krow < 264)
                kf = *(const s16x8*)&qkv[base + (size_t)krow * 384 + 128 + hq + quad * 8];
            f32x4 z = (f32x4){0.f, 0.f, 0.f, 0.f};
            sc[kt] = mfma16(qf, kf, z);
        }
        float mx[4] = {-1e30f, -1e30f, -1e30f, -1e30f};
        #pragma unroll
        for (int kt = 0; kt < 17; ++kt) {
            #pragma unroll
            for (int r = 0; r < 4; ++r) {
                float s = sc[kt][r] * 0.25f;             // 1/sqrt(16)
                if (kt == 16 && l16 >= 8) s = -1e30f;    // keys >= 264
                sc[kt][r] = s;
                mx[r] = fmaxf(mx[r], s);
            }
        }
        #pragma unroll
        for (int mk = 1; mk < 16; mk <<= 1)
            #pragma unroll
            for (int r = 0; r < 4; ++r) mx[r] = fmaxf(mx[r], __shfl_xor(mx[r], mk, 64));
        float lsum[4] = {0.f, 0.f, 0.f, 0.f};
        #pragma unroll
        for (int kt = 0; kt < 17; ++kt) {
            #pragma unroll
            for (int r = 0; r < 4; ++r) {
                float e = __expf(sc[kt][r] - mx[r]);
                lsum[r] += e;
                Pb[(wave * 16 + quad * 4 + r) * STR + kt * 16 + l16] = f2bf(e);
            }
        }
        #pragma unroll
        for (int mk = 1; mk < 16; mk <<= 1)
            #pragma unroll
            for (int r = 0; r < 4; ++r) lsum[r] += __shfl_xor(lsum[r], mk, 64);

        f32x4 oa = (f32x4){0.f, 0.f, 0.f, 0.f};
        #pragma unroll
        for (int kt2 = 0; kt2 < 9; ++kt2) {
            s16x8 pf = *(const s16x8*)&Pb[(wave * 16 + l16) * STR + kt2 * 32 + quad * 8];
            s16x8 vf = *(const s16x8*)&VT[l16 * STR + kt2 * 32 + quad * 8];
            oa = mfma16(pf, vf, oa);
        }
        #pragma unroll
        for (int r = 0; r < 4; ++r) {
            int row = q0 + quad * 4 + r;
            if (row < 264)
                ctx[((size_t)b * 264 + row) * 128 + hq + l16] = f2bf(oa[r] / lsum[r]);
        }
    }
}

// ---------------------------------------------------------------------------
extern "C" void kernel_launch(void* const* d_in, const int* in_sizes, int n_in,
                              void* d_out, int out_size, void* d_ws, size_t ws_size,
                              hipStream_t stream)
{
    (void)in_sizes; (void)n_in; (void)out_size; (void)ws_size;
    const float* x    = (const float*)d_in[0];
    const int*   tidx = (const int*)d_in[1];
    const int*   sidx = (const int*)d_in[2];
    const float* cw   = (const float*)d_in[3];
    const float* cb   = (const float*)d_in[4];
    const float* pos  = (const float*)d_in[5];
    const float* ttab = (const float*)d_in[6];
    const float* stab = (const float*)d_in[7];
    const float* cls  = (const float*)d_in[8];
    const float* Wqkv = (const float*)d_in[9];
    const float* bqkv = (const float*)d_in[10];
    const float* Wo   = (const float*)d_in[11];
    const float* bo   = (const float*)d_in[12];
    const float* W1   = (const float*)d_in[13];
    const float* b1   = (const float*)d_in[14];
    const float* W2   = (const float*)d_in[15];
    const float* b2   = (const float*)d_in[16];
    const float* g1   = (const float*)d_in[17];
    const float* be1  = (const float*)d_in[18];
    const float* g2   = (const float*)d_in[19];
    const float* be2  = (const float*)d_in[20];

    // workspace layout (bytes), total 65,273,856:
    //   h32  [33792,128] fp32 @ 0          (17301504)
    //   h16  [33792,128] bf16 @ 17301504   ( 8650752)
    //   big  [33792,512] bf16 @ 25952256   (34603008)  qkv(384)/ff1(512); x16 alias pre-layer0
    //   ctx  aliased @ 51904512 (8650752); cw16 alias pre-layer0
    //   bf16 weights @ 60555264: wqkv 1179648 | wo 393216 | w1 1572864 | w2 1572864
    char* ws = (char*)d_ws;
    float* h32 = (float*)ws;
    u16* h16    = (u16*)(ws + 17301504);
    u16* big    = (u16*)(ws + 25952256);
    u16* ctx    = (u16*)(ws + 51904512);
    u16* wqkv16 = (u16*)(ws + 60555264);
    u16* wo16   = (u16*)(ws + 61734912);
    u16* w116   = (u16*)(ws + 62128128);
    u16* w216   = (u16*)(ws + 63700992);
    u16* x16    = big;                    // [32256, 96] bf16, free before layer 0
    u16* cw16   = ctx;                    // [128, 96]  bf16, free before layer 0

    cvt_kernel<<<512, 256, 0, stream>>>(Wqkv, wqkv16, 12 * 384 * 128);
    cvt_kernel<<<256, 256, 0, stream>>>(Wo,   wo16,   12 * 128 * 128);
    cvt_kernel<<<512, 256, 0, stream>>>(W1,   w116,   12 * 512 * 128);
    cvt_kernel<<<512, 256, 0, stream>>>(W2,   w216,   12 * 128 * 512);
    cvt_kernel<<<1024, 256, 0, stream>>>(x,   x16,    128 * 252 * 96);
    cvt_kernel<<<48, 256, 0, stream>>>(cw,    cw16,   128 * 96);
    embed_cls_kernel<<<768, 256, 0, stream>>>(cls, pos, h32, h16);
    embed_mfma<<<504, 256, 0, stream>>>(x16, cw16, cb, pos, ttab, stab, tidx, sidx, h32, h16);

    for (int l = 0; l < 12; ++l) {
        gemm_direct<false, 4><<<dim3(528, 3), 256, 0, stream>>>(
            h16, wqkv16 + l * 384 * 128, bqkv + l * 384, big, 384);
        attn_kernel<<<1024, 256, 0, stream>>>(big, ctx);
        gemm_ln<128><<<528, 256, 0, stream>>>(
            ctx, wo16 + l * 128 * 128, bo + l * 128, h32, g1 + l * 128, be1 + l * 128, h32, h16);
        gemm_direct<true, 4><<<dim3(528, 4), 256, 0, stream>>>(
            h16, w116 + l * 512 * 128, b1 + l * 512, big, 512);
        float* o32 = (l == 11) ? (float*)d_out : h32;
        gemm_ln<512><<<528, 256, 0, stream>>>(
            big, w216 + l * 128 * 512, b2 + l * 128, h32, g2 + l * 128, be2 + l * 128, o32, h16);
    }
}

// Round 4
// 1360.161 us; speedup vs baseline: 1.5603x; 1.5603x over previous
//
#include <hip/hip_runtime.h>

typedef unsigned short u16;
typedef __attribute__((ext_vector_type(8))) short s16x8;
typedef __attribute__((ext_vector_type(4))) float f32x4;

__device__ __forceinline__ float bf2f(u16 u) {
    union { unsigned i; float f; } v; v.i = (unsigned)u << 16; return v.f;
}
__device__ __forceinline__ u16 f2bf(float f) {
    union { float f; unsigned i; } v; v.f = f;
    unsigned r = v.i + 0x7fffu + ((v.i >> 16) & 1u);
    return (u16)(r >> 16);
}
__device__ __forceinline__ f32x4 mfma16(s16x8 a, s16x8 b, f32x4 c) {
    return __builtin_amdgcn_mfma_f32_16x16x32_bf16(a, b, c, 0, 0, 0);
}

// ---------------------------------------------------------------------------
// fp32 -> bf16 conversion
// ---------------------------------------------------------------------------
__global__ __launch_bounds__(256)
void cvt_kernel(const float* __restrict__ src, u16* __restrict__ dst, int n)
{
    for (int i = blockIdx.x * 256 + threadIdx.x; i < n; i += gridDim.x * 256)
        dst[i] = f2bf(src[i]);
}

// ---------------------------------------------------------------------------
// cls rows: h[b, s<12, :] = cls[s] + pos[s]
// ---------------------------------------------------------------------------
__global__ __launch_bounds__(256)
void embed_cls_kernel(const float* __restrict__ cls, const float* __restrict__ pos,
                      float* __restrict__ h32, u16* __restrict__ h16)
{
    int i = blockIdx.x * 256 + threadIdx.x;           // < 128*12*128
    int e = i & 127, s = (i >> 7) % 12, b = i / (12 * 128);
    float v = cls[s * 128 + e] + pos[s * 128 + e];
    size_t o = ((size_t)b * 264 + s) * 128 + e;
    h32[o] = v; h16[o] = f2bf(v);
}

// ---------------------------------------------------------------------------
// Conv-embed via MFMA: rows = (b,l) flat [32256], K=96, N=128.
// ---------------------------------------------------------------------------
__global__ __launch_bounds__(256)
void embed_mfma(const u16* __restrict__ x16, const u16* __restrict__ cw16,
                const float* __restrict__ cb, const float* __restrict__ pos,
                const float* __restrict__ ttab, const float* __restrict__ stab,
                const int* __restrict__ tidx, const int* __restrict__ sidx,
                float* __restrict__ h32, u16* __restrict__ h16)
{
    const int t = threadIdx.x;
    const int wave = t >> 6, lane = t & 63;
    const int quad = lane >> 4, l16 = lane & 15;
    const int n0 = wave * 32;

    s16x8 wf[2][3];
    float bv[2];
    #pragma unroll
    for (int nt = 0; nt < 2; ++nt) {
        bv[nt] = cb[n0 + nt * 16 + l16];
        #pragma unroll
        for (int ks = 0; ks < 3; ++ks)
            wf[nt][ks] = *(const s16x8*)&cw16[(n0 + nt * 16 + l16) * 96 + ks * 32 + quad * 8];
    }
    #pragma unroll
    for (int tt = 0; tt < 4; ++tt) {
        const int m0 = (blockIdx.x * 4 + tt) * 16;
        s16x8 af[3];
        #pragma unroll
        for (int ks = 0; ks < 3; ++ks)
            af[ks] = *(const s16x8*)&x16[(size_t)(m0 + l16) * 96 + ks * 32 + quad * 8];
        f32x4 a0 = (f32x4){0.f,0.f,0.f,0.f}, a1 = (f32x4){0.f,0.f,0.f,0.f};
        #pragma unroll
        for (int ks = 0; ks < 3; ++ks) {
            a0 = mfma16(af[ks], wf[0][ks], a0);
            a1 = mfma16(af[ks], wf[1][ks], a1);
        }
        #pragma unroll
        for (int r = 0; r < 4; ++r) {
            int row = m0 + quad * 4 + r;
            int b = row / 252, l = row - b * 252;
            int ti = tidx[row], si = sidx[row];
            size_t tok = (size_t)b * 264 + 12 + l;
            #pragma unroll
            for (int nt = 0; nt < 2; ++nt) {
                int col = n0 + nt * 16 + l16;
                float v = (nt ? a1[r] : a0[r]) + bv[nt]
                        + pos[(12 + l) * 128 + col]
                        + ttab[ti * 128 + col] + stab[si * 128 + col];
                h32[tok * 128 + col] = v;
                h16[tok * 128 + col] = f2bf(v);
            }
        }
    }
}

// ---------------------------------------------------------------------------
// C[M,N] = act(A[M,K] @ W[N,K]^T + bias), bf16 A/W/C, fp32 bias.
// 64x64 block tile, 4 waves (proven R2 version).
// ---------------------------------------------------------------------------
template<bool RELU>
__global__ __launch_bounds__(256)
void gemm_bias(const u16* __restrict__ A, const u16* __restrict__ W,
               const float* __restrict__ bias, u16* __restrict__ C,
               int N, int K)
{
    const int LDK = 136;
    __shared__ alignas(16) u16 As[64 * 136];
    __shared__ alignas(16) u16 Ws[64 * 136];
    const int m0 = blockIdx.x * 64;
    const int n0 = blockIdx.y * 64;
    const int t = threadIdx.x;
    const int wave = t >> 6, lane = t & 63;
    const int quad = lane >> 4, l16 = lane & 15;
    const int wm = (wave & 1) * 32, wn = (wave >> 1) * 32;

    f32x4 acc[2][2];
    #pragma unroll
    for (int i = 0; i < 2; ++i)
        #pragma unroll
        for (int j = 0; j < 2; ++j) acc[i][j] = (f32x4){0.f, 0.f, 0.f, 0.f};

    for (int kc = 0; kc < K; kc += 128) {
        __syncthreads();
        #pragma unroll
        for (int i = 0; i < 4; ++i) {
            int id = i * 256 + t;
            int row = id >> 4, c8 = (id & 15) << 3;
            *(uint4*)&As[row * LDK + c8] = *(const uint4*)&A[(size_t)(m0 + row) * K + kc + c8];
            *(uint4*)&Ws[row * LDK + c8] = *(const uint4*)&W[(size_t)(n0 + row) * K + kc + c8];
        }
        __syncthreads();
        #pragma unroll
        for (int ks = 0; ks < 4; ++ks) {
            s16x8 a0 = *(const s16x8*)&As[(wm + l16) * LDK + ks * 32 + quad * 8];
            s16x8 a1 = *(const s16x8*)&As[(wm + 16 + l16) * LDK + ks * 32 + quad * 8];
            s16x8 b0 = *(const s16x8*)&Ws[(wn + l16) * LDK + ks * 32 + quad * 8];
            s16x8 b1 = *(const s16x8*)&Ws[(wn + 16 + l16) * LDK + ks * 32 + quad * 8];
            acc[0][0] = mfma16(a0, b0, acc[0][0]);
            acc[0][1] = mfma16(a0, b1, acc[0][1]);
            acc[1][0] = mfma16(a1, b0, acc[1][0]);
            acc[1][1] = mfma16(a1, b1, acc[1][1]);
        }
    }
    #pragma unroll
    for (int ni = 0; ni < 2; ++ni) {
        int col = n0 + wn + ni * 16 + l16;
        float bv = bias[col];
        #pragma unroll
        for (int mi = 0; mi < 2; ++mi) {
            #pragma unroll
            for (int r = 0; r < 4; ++r) {
                int row = m0 + wm + mi * 16 + quad * 4 + r;
                float v = acc[mi][ni][r] + bv;
                if (RELU) v = fmaxf(v, 0.f);
                C[(size_t)row * N + col] = f2bf(v);
            }
        }
    }
}

// ---------------------------------------------------------------------------
// Fused: y = LN(A[M,K] @ W[128,K]^T + bias + resid), write fp32 + bf16.
// ---------------------------------------------------------------------------
template<int K>
__global__ __launch_bounds__(256)
void gemm_ln(const u16* __restrict__ A, const u16* __restrict__ W,
             const float* __restrict__ bias, const float* resid,
             const float* __restrict__ g, const float* __restrict__ be,
             float* o32, u16* o16)
{
    const int LDK = 136;
    __shared__ alignas(16) u16 As[64 * 136];
    __shared__ alignas(16) u16 Ws[128 * 136];
    const int m0 = blockIdx.x * 64;
    const int t = threadIdx.x;
    const int wave = t >> 6, lane = t & 63;
    const int quad = lane >> 4, l16 = lane & 15;
    const int wr = wave * 16;

    f32x4 acc[8];
    #pragma unroll
    for (int i = 0; i < 8; ++i) acc[i] = (f32x4){0.f, 0.f, 0.f, 0.f};

    for (int kc = 0; kc < K; kc += 128) {
        __syncthreads();
        #pragma unroll
        for (int i = 0; i < 4; ++i) {
            int id = i * 256 + t;
            int row = id >> 4, c8 = (id & 15) << 3;
            *(uint4*)&As[row * LDK + c8] = *(const uint4*)&A[(size_t)(m0 + row) * K + kc + c8];
        }
        #pragma unroll
        for (int i = 0; i < 8; ++i) {
            int id = i * 256 + t;
            int row = id >> 4, c8 = (id & 15) << 3;
            *(uint4*)&Ws[row * LDK + c8] = *(const uint4*)&W[(size_t)row * K + kc + c8];
        }
        __syncthreads();
        #pragma unroll
        for (int ks = 0; ks < 4; ++ks) {
            s16x8 a = *(const s16x8*)&As[(wr + l16) * LDK + ks * 32 + quad * 8];
            #pragma unroll
            for (int nt = 0; nt < 8; ++nt) {
                s16x8 b = *(const s16x8*)&Ws[(nt * 16 + l16) * LDK + ks * 32 + quad * 8];
                acc[nt] = mfma16(a, b, acc[nt]);
            }
        }
    }
    #pragma unroll
    for (int nt = 0; nt < 8; ++nt) {
        int col = nt * 16 + l16;
        float bv = bias[col];
        #pragma unroll
        for (int r = 0; r < 4; ++r) {
            int row = m0 + wr + quad * 4 + r;
            acc[nt][r] += bv + resid[(size_t)row * 128 + col];
        }
    }
    float sm[4], sq[4];
    #pragma unroll
    for (int r = 0; r < 4; ++r) {
        float s = 0.f, q = 0.f;
        #pragma unroll
        for (int nt = 0; nt < 8; ++nt) { float v = acc[nt][r]; s += v; q += v * v; }
        sm[r] = s; sq[r] = q;
    }
    #pragma unroll
    for (int mk = 1; mk < 16; mk <<= 1) {
        #pragma unroll
        for (int r = 0; r < 4; ++r) {
            sm[r] += __shfl_xor(sm[r], mk, 64);
            sq[r] += __shfl_xor(sq[r], mk, 64);
        }
    }
    #pragma unroll
    for (int r = 0; r < 4; ++r) {
        float mean = sm[r] * (1.f / 128.f);
        float var = sq[r] * (1.f / 128.f) - mean * mean;
        float rstd = rsqrtf(var + 1e-5f);
        int row = m0 + wr + quad * 4 + r;
        #pragma unroll
        for (int nt = 0; nt < 8; ++nt) {
            int col = nt * 16 + l16;
            float y = (acc[nt][r] - mean) * rstd * g[col] + be[col];
            o32[(size_t)row * 128 + col] = y;
            o16[(size_t)row * 128 + col] = f2bf(y);
        }
    }
}

// ---------------------------------------------------------------------------
// Attention v2: transpose-free. One block per (b, head), 4 waves.
// Scores computed TRANSPOSED (scT[key][q]): a=K-frag, b=Q-frag. C-layout of
// scT (lane: key=quad*4+r, q=l16) is EXACTLY the A-fragment of P for the PV
// MFMA under a permuted k-ordering (k-slot quad*8+j <-> key kt*16+quad*4+j);
// V-fragments load with the same permutation (two ds_read_b64 from VT).
// No P round trip, no Pb buffer. K staged once in LDS (stride 24 u16).
// ---------------------------------------------------------------------------
__global__ __launch_bounds__(256)
void attn_kernel(const u16* __restrict__ qkv, u16* __restrict__ ctx)
{
    const int STR = 296;  // VT: [d=16][key padded], keys 264..295 zeroed
    const int KLD = 24;   // Ks: [key=272][d=16 pad 24] (48B rows, 16B-aligned)
    __shared__ alignas(16) u16 VT[16 * STR];    // 9472 B
    __shared__ alignas(16) u16 Ks[272 * KLD];   // 13056 B
    const int b = blockIdx.x >> 3, h = blockIdx.x & 7;
    const size_t base = (size_t)b * 264 * 384;
    const int t = threadIdx.x;
    const int wave = t >> 6, lane = t & 63;
    const int quad = lane >> 4, l16 = lane & 15;
    const int hq = h * 16;

    // stage K rows (vectorized 16B both sides)
    for (int i = t; i < 264 * 2; i += 256) {
        int key = i >> 1, dq = (i & 1) * 8;
        *(uint4*)&Ks[key * KLD + dq] =
            *(const uint4*)&qkv[base + (size_t)key * 384 + 128 + hq + dq];
    }
    // stage V transposed + zero-pad keys 264..295
    for (int i = t; i < 264 * 16; i += 256) {
        int s = i >> 4, d = i & 15;
        VT[d * STR + s] = qkv[base + (size_t)s * 384 + 256 + hq + d];
    }
    for (int i = t; i < 16 * 32; i += 256) {
        int d = i >> 5, c = 264 + (i & 31);
        VT[d * STR + c] = 0;
    }
    __syncthreads();

    for (int qt = wave; qt < 17; qt += 4) {
        const int q0 = qt * 16;
        // Q-frag (b-operand): lane l16 = q, k = d = quad*8+j (quads 2,3 zero)
        s16x8 qf = (s16x8){0, 0, 0, 0, 0, 0, 0, 0};
        {
            int qrow = q0 + l16;
            if (quad < 2 && qrow < 264)
                qf = *(const s16x8*)&qkv[base + (size_t)qrow * 384 + hq + quad * 8];
        }
        // scores transposed: scT[key=quad*4+r][q=l16], per kt block of 16 keys
        f32x4 sc[17];
        #pragma unroll
        for (int kt = 0; kt < 17; ++kt) {
            s16x8 kf = (s16x8){0, 0, 0, 0, 0, 0, 0, 0};
            if (quad < 2)
                kf = *(const s16x8*)&Ks[(kt * 16 + l16) * KLD + quad * 8];
            f32x4 z = (f32x4){0.f, 0.f, 0.f, 0.f};
            sc[kt] = mfma16(kf, qf, z);
        }
        // softmax over keys (per q = per l16; reduce across quads via shfl)
        float mx = -1e30f;
        #pragma unroll
        for (int kt = 0; kt < 17; ++kt) {
            #pragma unroll
            for (int r = 0; r < 4; ++r) {
                float s = sc[kt][r] * 0.25f;                 // 1/sqrt(16)
                if (kt == 16 && quad >= 2) s = -1e30f;       // keys >= 264
                sc[kt][r] = s;
                mx = fmaxf(mx, s);
            }
        }
        mx = fmaxf(mx, __shfl_xor(mx, 16, 64));
        mx = fmaxf(mx, __shfl_xor(mx, 32, 64));
        float ls = 0.f;
        #pragma unroll
        for (int kt = 0; kt < 17; ++kt) {
            #pragma unroll
            for (int r = 0; r < 4; ++r) {
                float e = __expf(sc[kt][r] - mx);
                sc[kt][r] = e;
                ls += e;
            }
        }
        ls += __shfl_xor(ls, 16, 64);
        ls += __shfl_xor(ls, 32, 64);
        float rinv = 1.f / ls;

        // PV: 9 chunks of 32 permuted keys (kt pair), P direct from sc regs
        f32x4 oa = (f32x4){0.f, 0.f, 0.f, 0.f};
        #pragma unroll
        for (int c = 0; c < 9; ++c) {
            const int kt0 = 2 * c, kt1 = 2 * c + 1;   // kt1==17 -> VT zero pad
            union { s16x8 v; u16 u[8]; } pk;
            #pragma unroll
            for (int j = 0; j < 4; ++j) pk.u[j] = f2bf(sc[kt0][j] * rinv);
            #pragma unroll
            for (int j = 0; j < 4; ++j)
                pk.u[4 + j] = (c == 8) ? (u16)0 : f2bf(sc[kt1][j] * rinv);
            union { s16x8 v; uint2 h2[2]; } vt;
            vt.h2[0] = *(const uint2*)&VT[l16 * STR + kt0 * 16 + quad * 4];
            vt.h2[1] = *(const uint2*)&VT[l16 * STR + kt1 * 16 + quad * 4];
            oa = mfma16(pk.v, vt.v, oa);
        }
        #pragma unroll
        for (int r = 0; r < 4; ++r) {
            int row = q0 + quad * 4 + r;
            if (row < 264)
                ctx[((size_t)b * 264 + row) * 128 + hq + l16] = f2bf(oa[r]);
        }
    }
}

// ---------------------------------------------------------------------------
extern "C" void kernel_launch(void* const* d_in, const int* in_sizes, int n_in,
                              void* d_out, int out_size, void* d_ws, size_t ws_size,
                              hipStream_t stream)
{
    (void)in_sizes; (void)n_in; (void)out_size; (void)ws_size;
    const float* x    = (const float*)d_in[0];
    const int*   tidx = (const int*)d_in[1];
    const int*   sidx = (const int*)d_in[2];
    const float* cw   = (const float*)d_in[3];
    const float* cb   = (const float*)d_in[4];
    const float* pos  = (const float*)d_in[5];
    const float* ttab = (const float*)d_in[6];
    const float* stab = (const float*)d_in[7];
    const float* cls  = (const float*)d_in[8];
    const float* Wqkv = (const float*)d_in[9];
    const float* bqkv = (const float*)d_in[10];
    const float* Wo   = (const float*)d_in[11];
    const float* bo   = (const float*)d_in[12];
    const float* W1   = (const float*)d_in[13];
    const float* b1   = (const float*)d_in[14];
    const float* W2   = (const float*)d_in[15];
    const float* b2   = (const float*)d_in[16];
    const float* g1   = (const float*)d_in[17];
    const float* be1  = (const float*)d_in[18];
    const float* g2   = (const float*)d_in[19];
    const float* be2  = (const float*)d_in[20];

    char* ws = (char*)d_ws;
    float* h32 = (float*)ws;
    u16* h16    = (u16*)(ws + 17301504);
    u16* big    = (u16*)(ws + 25952256);
    u16* ctx    = (u16*)(ws + 51904512);
    u16* wqkv16 = (u16*)(ws + 60555264);
    u16* wo16   = (u16*)(ws + 61734912);
    u16* w116   = (u16*)(ws + 62128128);
    u16* w216   = (u16*)(ws + 63700992);
    u16* x16    = big;                    // [32256, 96] bf16, free before layer 0
    u16* cw16   = ctx;                    // [128, 96]  bf16, free before layer 0

    cvt_kernel<<<512, 256, 0, stream>>>(Wqkv, wqkv16, 12 * 384 * 128);
    cvt_kernel<<<256, 256, 0, stream>>>(Wo,   wo16,   12 * 128 * 128);
    cvt_kernel<<<512, 256, 0, stream>>>(W1,   w116,   12 * 512 * 128);
    cvt_kernel<<<512, 256, 0, stream>>>(W2,   w216,   12 * 128 * 512);
    cvt_kernel<<<1024, 256, 0, stream>>>(x,   x16,    128 * 252 * 96);
    cvt_kernel<<<48, 256, 0, stream>>>(cw,    cw16,   128 * 96);
    embed_cls_kernel<<<768, 256, 0, stream>>>(cls, pos, h32, h16);
    embed_mfma<<<504, 256, 0, stream>>>(x16, cw16, cb, pos, ttab, stab, tidx, sidx, h32, h16);

    for (int l = 0; l < 12; ++l) {
        gemm_bias<false><<<dim3(528, 6), 256, 0, stream>>>(
            h16, wqkv16 + l * 384 * 128, bqkv + l * 384, big, 384, 128);
        attn_kernel<<<1024, 256, 0, stream>>>(big, ctx);
        gemm_ln<128><<<528, 256, 0, stream>>>(
            ctx, wo16 + l * 128 * 128, bo + l * 128, h32, g1 + l * 128, be1 + l * 128, h32, h16);
        gemm_bias<true><<<dim3(528, 8), 256, 0, stream>>>(
            h16, w116 + l * 512 * 128, b1 + l * 512, big, 512, 128);
        float* o32 = (l == 11) ? (float*)d_out : h32;
        gemm_ln<512><<<528, 256, 0, stream>>>(
            big, w216 + l * 128 * 512, b2 + l * 128, h32, g2 + l * 128, be2 + l * 128, o32, h16);
    }
}